// Round 1
// 1394.414 us; speedup vs baseline: 1.0215x; 1.0215x over previous
//
#include <hip/hip_runtime.h>
#include <hip/hip_bf16.h>

// Problem constants
#define BATCH 2
#define CIN 512
#define COUT 512
#define RES 256
#define WDIM 512
#define GRIDP 8
#define PW 32          // patch width = RES/GRIDP
#define NPATCH 16      // BATCH*GRIDP
#define LRELU 0.2f
#define ACT_GAIN 1.41421356237309515f

typedef __attribute__((ext_vector_type(8))) short bf16x8;   // 8 bf16 in 4 VGPRs
typedef __attribute__((ext_vector_type(4))) float f32x4;

// Workspace layout (bytes)
#define SZ_XMOD (134217728ULL)                 // [16][256][32][512] bf16
#define OFF_WBF (SZ_XMOD)                      // [9][512][512] bf16
#define SZ_WBF  (9ULL*512*512*2)
#define OFF_STYLES (OFF_WBF + SZ_WBF)          // [2][3][512] f32
#define SZ_STYLES (2*3*512*4)
#define OFF_INVSTD (OFF_STYLES + SZ_STYLES)    // [2][512][8] f32
#define SZ_INVSTD (2*512*8*4)
#define OFF_DEMOD (OFF_INVSTD + SZ_INVSTD)     // [512] f32

// async global->LDS, 16B per lane, linear LDS dest (wave-uniform base + lane*16)
#define GLOAD16(gp, lp) __builtin_amdgcn_global_load_lds( \
    (const __attribute__((address_space(1))) void*)(gp),  \
    (__attribute__((address_space(3))) void*)(lp), 16, 0, 0)

// ---------------- Kernel 1: styles = wg @ affine_w^T / sqrt(512) + affine_b ----
__global__ void k_styles(const float* __restrict__ w, const float* __restrict__ wctx,
                         const float* __restrict__ affw, const float* __restrict__ affb,
                         float* __restrict__ styles) {
    int tid = blockIdx.x * 256 + threadIdx.x;
    if (tid >= BATCH * 3 * CIN) return;
    int c = tid & 511;
    int s = (tid >> 9) % 3;
    int b = tid / (3 * 512);
    const float* row = (s == 0) ? (wctx + b * 2 * WDIM)
                     : (s == 1) ? (w + b * WDIM)
                                : (wctx + b * 2 * WDIM + WDIM);
    const float* aw = affw + (size_t)c * WDIM;
    float acc = 0.f;
    for (int d = 0; d < WDIM; ++d) acc += row[d] * aw[d];
    styles[tid] = acc * 0.044194173824159216f + affb[c];
}

// ---------------- Kernel 2: weight -> bf16 [tap][cout][cin], demod[cout] -------
__global__ void k_wprep(const float* __restrict__ weight, __hip_bfloat16* __restrict__ wbf,
                        float* __restrict__ demod) {
    int o = blockIdx.x;          // cout
    int t = threadIdx.x;
    const float* wrow = weight + (size_t)o * 4608;
    float ss = 0.f;
    for (int i = t; i < 4608; i += 256) { float v = wrow[i]; ss += v * v; }
    #pragma unroll
    for (int off = 32; off; off >>= 1) ss += __shfl_down(ss, off, 64);
    __shared__ float red[4];
    if ((t & 63) == 0) red[t >> 6] = ss;
    __syncthreads();
    if (t == 0) {
        float tot = red[0] + red[1] + red[2] + red[3];
        demod[o] = 1.0f / sqrtf(tot + 1e-8f);
    }
    // rearrange: wbf[k][o][ci] = bf16(weight[o][ci][kh][kw]), k = kh*3+kw
    for (int k = 0; k < 9; ++k)
        for (int ci = t; ci < 512; ci += 256)
            wbf[(size_t)k * COUT * CIN + (size_t)o * CIN + ci] = __float2bfloat16(wrow[ci * 9 + k]);
}

// ---------------- Kernel 3: per-(b,c,patch) inv_std (ddof=1) -------------------
__global__ void k_std(const float* __restrict__ x, float* __restrict__ inv_std) {
    int bid = blockIdx.x;                 // [b][c][g]
    int g = bid & 7;
    int c = (bid >> 3) & 511;
    int b = bid >> 12;
    const float* base = x + ((size_t)(b * 512 + c) * 256) * 256 + g * 32;
    int t = threadIdx.x;
    float s = 0.f, ss = 0.f;
    #pragma unroll 4
    for (int i = 0; i < 32; ++i) {
        int e = t + (i << 8);
        int h = e >> 5, wp = e & 31;
        float v = base[h * 256 + wp];
        s += v; ss += v * v;
    }
    #pragma unroll
    for (int off = 32; off; off >>= 1) {
        s += __shfl_down(s, off, 64);
        ss += __shfl_down(ss, off, 64);
    }
    __shared__ float rs[4], rss[4];
    if ((t & 63) == 0) { rs[t >> 6] = s; rss[t >> 6] = ss; }
    __syncthreads();
    if (t == 0) {
        float S = rs[0] + rs[1] + rs[2] + rs[3];
        float SS = rss[0] + rss[1] + rss[2] + rss[3];
        float var = (SS - S * S * (1.f / 8192.f)) * (1.f / 8191.f);
        var = fmaxf(var, 0.f);
        inv_std[bid] = 1.f / (sqrtf(var) + 1e-8f);
    }
}

// ---------------- Kernel 4: normalize * style-lerp -> bf16, transpose ----------
// out layout: xmod[p][h][wp][cin]  (cin contiguous for conv staging)
__global__ void k_normmod(const float* __restrict__ x, const float* __restrict__ styles,
                          const float* __restrict__ inv_std, const int* __restrict__ lbi,
                          __hip_bfloat16* __restrict__ xmod) {
    int bid = blockIdx.x;
    int ht = bid & 31;           // h-tile of 8 rows
    int cc = (bid >> 5) & 7;     // cin chunk of 64
    int p = bid >> 8;            // patch
    int b = p >> 3, g = p & 7;
    int t = threadIdx.x;
    __shared__ float st[3][64];
    __shared__ float istd[64];
    __shared__ __align__(16) __hip_bfloat16 tile[8 * 33 * 66];
    if (t < 192) {
        int s = t / 64, c = t % 64;
        st[s][c] = styles[(b * 3 + s) * 512 + cc * 64 + c];
    } else {
        int c = t - 192;
        istd[c] = inv_std[(b * 512 + cc * 64 + c) * 8 + g];
    }
    __syncthreads();
    float center = (float)(lbi[b] * PW);
    const float* xb = x + ((size_t)(b * 512 + cc * 64) * 256 + ht * 8) * 256 + g * 32;
    #pragma unroll 4
    for (int i = 0; i < 16; ++i) {
        int cell = t + (i << 8);         // over [c:64][h:8][v4:8]
        int c = cell >> 6;
        int rem = cell & 63;
        int h = rem >> 3;
        int v4 = rem & 7;
        float4 xv = *(const float4*)(xb + ((size_t)c * 256 + h) * 256 + v4 * 4);
        float sc = istd[c];
        float s0 = st[0][c], s1 = st[1][c], s2 = st[2][c];
        float colb = (float)(g * 32 + v4 * 4) + 0.5f;
        const float* xvp = &xv.x;
        #pragma unroll
        for (int k = 0; k < 4; ++k) {
            float tc = (colb + (float)k - center) * 0.00390625f;  // /256
            tc = fminf(fmaxf(tc, -1.f), 1.f);
            float a = fmaxf(-tc, 0.f), r = fmaxf(tc, 0.f);
            float m = 1.f - a - r;
            float scol = a * s0 + m * s1 + r * s2;
            tile[(h * 33 + (v4 * 4 + k)) * 66 + c] = __float2bfloat16(xvp[k] * sc * scol);
        }
    }
    __syncthreads();
    __hip_bfloat16* ob = xmod + (size_t)(p * 256 + ht * 8) * 32 * 512 + cc * 64;
    #pragma unroll 4
    for (int i = 0; i < 8; ++i) {
        int cell = t + (i << 8);         // over [h:8][wp:32][c8:8]
        int c8 = cell & 7;
        int wp = (cell >> 3) & 31;
        int h = cell >> 8;
        const __hip_bfloat16* src = tile + (h * 33 + wp) * 66 + c8 * 8;
        uint4 v;
        v.x = *(const unsigned*)(src);
        v.y = *(const unsigned*)(src + 2);
        v.z = *(const unsigned*)(src + 4);
        v.w = *(const unsigned*)(src + 6);
        *(uint4*)(ob + (size_t)(h * 32 + wp) * 512 + c8 * 8) = v;
    }
}

// ---------------- Kernel 5: patchwise 3x3 conv via MFMA + fused epilogue -------
// grid: (32 h-tiles of 8 rows, 16 patches, 4 cout-blocks), block 256 = 4 waves
// block tile: 128 cout x 256 spatial (8h x 32wp); wave tile 128 cout x 64 spatial
// (all 4 waves share the 128-cout range; wave w owns h rows {2w, 2w+1})
// wsA: double-buffered, filled by global_load_lds (linear LDS, swizzle applied on
// the global source address: cell(kw,r,c4) holds cin-subchunk k8 = c4 ^ ((r>>1)&3))
// xsB: reg-staged once per cin0 (T14: loads issued during previous kh=2 phase)
__global__ void __launch_bounds__(256, 2)
k_conv(const __hip_bfloat16* __restrict__ xmod, const __hip_bfloat16* __restrict__ wbf,
       const float* __restrict__ demod, const float* __restrict__ bias,
       const float* __restrict__ noise, const float* __restrict__ nstr_p,
       float* __restrict__ out) {
    const int ht = blockIdx.x;     // 0..31
    const int p  = blockIdx.y;     // 0..15
    const int mb = blockIdx.z;     // 0..3
    const int b = p >> 3, g = p & 7;
    const int cout0 = mb * 128;
    const int h0b = ht * 8;
    const int t = threadIdx.x;
    const int lane = t & 63, wid = t >> 6;
    const int l15 = lane & 15, q = lane >> 4;
    const int sw = (l15 >> 1) & 3;
    const int qs = q ^ sw;

    // wsA[pb][kw:3][r:128][c4:4][8 cin] -- 2 x 24576 B ; xsB[k8:4][hs:10][wps:34][8 cin]
    __shared__ __align__(16) __hip_bfloat16 wsA[2 * 3 * 128 * 32];  // 49152 B
    __shared__ __align__(16) __hip_bfloat16 xsB[4 * 10 * 34 * 8];   // 21760 B

    // ---- xsB staging descriptors: 1360 cells of 16B, 6 per thread (last partial)
    int xgo[6]; int xlo[6]; bool xin[6]; bool xld[6];
    #pragma unroll
    for (int i = 0; i < 6; ++i) {
        int idx = t + i * 256;
        int k8 = idx / 340;
        int rem = idx - k8 * 340;
        int hs = rem / 34;
        int wps = rem - hs * 34;
        int hg = h0b + hs - 1;
        xin[i] = idx < 1360;
        xld[i] = xin[i] && (wps >= 1) && (wps <= 32) && (hg >= 0) && (hg < 256);
        xgo[i] = (hg * 32 + (wps - 1)) * 512 + k8 * 8;
        xlo[i] = ((k8 * 10 + hs) * 34 + wps) * 8;
    }

    // ---- wsA gload descriptors: 24 chunks of 1KB, 6 per wave; per-lane global
    // address carries the inverse swizzle so the linear LDS image is swizzled.
    int wgo[6];
    #pragma unroll
    for (int i = 0; i < 6; ++i) {
        int idx = (wid * 6 + i) * 64 + lane;   // linear 16B-cell index in wsA buf
        int kw = idx >> 9;
        int r  = (idx >> 2) & 127;
        int c4 = idx & 3;
        int k8 = c4 ^ ((r >> 1) & 3);
        wgo[i] = kw * 262144 + (cout0 + r) * 512 + k8 * 8;
    }

    const __hip_bfloat16* xpat = xmod + (size_t)p * 256 * 32 * 512;
    const __hip_bfloat16* xb = xsB + ((q * 10 + wid * 2) * 34 + l15) * 8;

    f32x4 acc[8][4];
    #pragma unroll
    for (int mf = 0; mf < 8; ++mf)
        #pragma unroll
        for (int j = 0; j < 4; ++j) acc[mf][j] = (f32x4){0.f, 0.f, 0.f, 0.f};

    // ---- prologue: issue x slab (cin0=0) into regs, W(phase0) into wsA buf0
    uint4 xw[6];
    #pragma unroll
    for (int i = 0; i < 6; ++i) {
        uint4 v = make_uint4(0u, 0u, 0u, 0u);
        if (xld[i]) v = *(const uint4*)(xpat + xgo[i]);
        xw[i] = v;
    }
    {
        __hip_bfloat16* ldst = wsA + wid * 6 * 512;
        #pragma unroll
        for (int i = 0; i < 6; ++i)
            GLOAD16(wbf + wgo[i], ldst + i * 512);
    }

    int pb = 0;
    for (int cin0 = 0; cin0 < 512; cin0 += 32) {
        #pragma unroll
        for (int kh = 0; kh < 3; ++kh) {
            // phase barrier: W(current phase) arrived (vmcnt), all readers of the
            // buffers we are about to overwrite are done (lgkm + barrier)
            asm volatile("s_waitcnt vmcnt(0) lgkmcnt(0)" ::: "memory");
            __builtin_amdgcn_s_barrier();

            if (kh == 0) {
                // write staged x slab for this cin0
                #pragma unroll
                for (int i = 0; i < 6; ++i)
                    if (xin[i]) *(uint4*)(xsB + xlo[i]) = xw[i];
            }
            // issue next phase's weights into the other buffer
            if (!((cin0 == 480) && (kh == 2))) {
                int nkh  = (kh == 2) ? 0 : kh + 1;
                int ncin = (kh == 2) ? cin0 + 32 : cin0;
                const __hip_bfloat16* wsrc = wbf + nkh * 786432 + ncin;
                __hip_bfloat16* ldst = wsA + (pb ^ 1) * 12288 + wid * 6 * 512;
                #pragma unroll
                for (int i = 0; i < 6; ++i)
                    GLOAD16(wsrc + wgo[i], ldst + i * 512);
            }
            if (kh == 0) {
                // make xsB writes visible before compute reads them
                asm volatile("s_waitcnt lgkmcnt(0)" ::: "memory");
                __builtin_amdgcn_s_barrier();
            }
            if (kh == 2 && cin0 < 480) {
                // T14: issue next cin0's x slab loads; they complete under this
                // phase's MFMAs (no vmcnt(0) until next phase barrier)
                #pragma unroll
                for (int i = 0; i < 6; ++i) {
                    uint4 v = make_uint4(0u, 0u, 0u, 0u);
                    if (xld[i]) v = *(const uint4*)(xpat + xgo[i] + cin0 + 32);
                    xw[i] = v;
                }
            }

            // ---- compute this phase: 3 kw x (8 af + 4 bfr reads, 32 MFMA)
            const __hip_bfloat16* wb = wsA + pb * 12288 + l15 * 32 + qs * 8;
            #pragma unroll
            for (int kw = 0; kw < 3; ++kw) {
                bf16x8 af[8];
                #pragma unroll
                for (int mf = 0; mf < 8; ++mf)
                    af[mf] = *(const bf16x8*)(wb + kw * 4096 + mf * 512);
                #pragma unroll
                for (int j = 0; j < 4; ++j) {
                    bf16x8 bj = *(const bf16x8*)(xb + (((j >> 1) + kh) * 34 + (j & 1) * 16 + kw) * 8);
                    #pragma unroll
                    for (int mf = 0; mf < 8; ++mf)
                        acc[mf][j] = __builtin_amdgcn_mfma_f32_16x16x32_bf16(af[mf], bj, acc[mf][j], 0, 0, 0);
                }
            }
            pb ^= 1;
        }
    }

    // ---- epilogue: demod, noise, bias, lrelu*sqrt(2)
    float nstr = nstr_p[0];
    float nv[4];
    #pragma unroll
    for (int j = 0; j < 4; ++j) {
        int hg = h0b + wid * 2 + (j >> 1);
        int colg = g * 32 + (j & 1) * 16 + l15;
        nv[j] = noise[(size_t)b * 65536 + hg * 256 + colg] * nstr;
    }
    #pragma unroll
    for (int mf = 0; mf < 8; ++mf) {
        #pragma unroll
        for (int r = 0; r < 4; ++r) {
            int c = cout0 + mf * 16 + q * 4 + r;
            float dm = demod[c];
            float bi = bias[c];
            #pragma unroll
            for (int j = 0; j < 4; ++j) {
                int hg = h0b + wid * 2 + (j >> 1);
                int colg = g * 32 + (j & 1) * 16 + l15;
                float v = acc[mf][j][r] * dm + nv[j] + bi;
                v = (v >= 0.f ? v : v * LRELU) * ACT_GAIN;
                out[((size_t)(b * 512 + c) * 256 + hg) * 256 + colg] = v;
            }
        }
    }
}

// ---------------- host ----------------
extern "C" void kernel_launch(void* const* d_in, const int* in_sizes, int n_in,
                              void* d_out, int out_size, void* d_ws, size_t ws_size,
                              hipStream_t stream) {
    const float* x      = (const float*)d_in[0];
    const float* w      = (const float*)d_in[1];
    const float* wctx   = (const float*)d_in[2];
    const float* weight = (const float*)d_in[3];
    const float* affw   = (const float*)d_in[4];
    const float* affb   = (const float*)d_in[5];
    const float* bias   = (const float*)d_in[6];
    const float* nstr   = (const float*)d_in[7];
    const float* noise  = (const float*)d_in[8];
    const int*   lbi    = (const int*)d_in[9];
    float* out = (float*)d_out;

    char* wsb = (char*)d_ws;
    __hip_bfloat16* xmod = (__hip_bfloat16*)wsb;
    __hip_bfloat16* wbf  = (__hip_bfloat16*)(wsb + OFF_WBF);
    float* styles        = (float*)(wsb + OFF_STYLES);
    float* invstd        = (float*)(wsb + OFF_INVSTD);
    float* demod         = (float*)(wsb + OFF_DEMOD);

    k_styles<<<12, 256, 0, stream>>>(w, wctx, affw, affb, styles);
    k_wprep<<<512, 256, 0, stream>>>(weight, wbf, demod);
    k_std<<<8192, 256, 0, stream>>>(x, invstd);
    k_normmod<<<4096, 256, 0, stream>>>(x, styles, invstd, lbi, xmod);
    k_conv<<<dim3(32, 16, 4), 256, 0, stream>>>(xmod, wbf, demod, bias, noise, nstr, out);
}